// Round 1
// baseline (15306.633 us; speedup 1.0000x reference)
//
#include <hip/hip_runtime.h>
#include <math.h>

// ---------------------------------------------------------------------------
// MinVQVAE forward on MI355X — Round 0: all-fp32 baseline (VALU FMA GEMMs).
// B=4096, INPUT_DIM=3072, N_CAT=1024, D_LAT=256, N_Q=32, N_HID=4096.
// ---------------------------------------------------------------------------

#define BM 128
#define BN 128
#define BK 16

// ACT: 0 = none, 1 = exact GELU (erf), 2 = sigmoid + fused sum((x-pred)^2)
template<int ACT>
__global__ __launch_bounds__(256) void gemm_nt(
    const float* __restrict__ A, const float* __restrict__ Bw,
    const float* __restrict__ bias, float* __restrict__ C,
    int M, int N, int K,
    const float* __restrict__ Xref, float* __restrict__ sse_acc)
{
    __shared__ float As[BK][BM + 4];
    __shared__ float Bs[BK][BN + 4];
    __shared__ float red[4];

    const int tid = threadIdx.x;
    const int tx = tid & 15;          // 16 col-groups
    const int ty = tid >> 4;          // 16 row-groups
    const int m0 = blockIdx.y * BM;
    const int n0 = blockIdx.x * BN;
    const int lr = tid >> 2;          // 0..63 (row within half-tile)
    const int lk = (tid & 3) << 2;    // 0,4,8,12 (k offset)

    float acc[8][8];
    #pragma unroll
    for (int i = 0; i < 8; ++i)
        #pragma unroll
        for (int j = 0; j < 8; ++j) acc[i][j] = 0.0f;

    const float* Ap = A + (size_t)(m0 + lr) * K + lk;
    const float* Bp = Bw + (size_t)(n0 + lr) * K + lk;
    const size_t strideR = (size_t)64 * K;

    for (int k0 = 0; k0 < K; k0 += BK) {
        float4 a0 = *(const float4*)(Ap + k0);
        float4 a1 = *(const float4*)(Ap + k0 + strideR);
        float4 b0 = *(const float4*)(Bp + k0);
        float4 b1 = *(const float4*)(Bp + k0 + strideR);
        __syncthreads();
        As[lk+0][lr]    = a0.x; As[lk+1][lr]    = a0.y; As[lk+2][lr]    = a0.z; As[lk+3][lr]    = a0.w;
        As[lk+0][lr+64] = a1.x; As[lk+1][lr+64] = a1.y; As[lk+2][lr+64] = a1.z; As[lk+3][lr+64] = a1.w;
        Bs[lk+0][lr]    = b0.x; Bs[lk+1][lr]    = b0.y; Bs[lk+2][lr]    = b0.z; Bs[lk+3][lr]    = b0.w;
        Bs[lk+0][lr+64] = b1.x; Bs[lk+1][lr+64] = b1.y; Bs[lk+2][lr+64] = b1.z; Bs[lk+3][lr+64] = b1.w;
        __syncthreads();
        #pragma unroll
        for (int kk = 0; kk < BK; ++kk) {
            float a_[8], b_[8];
            *(float4*)&a_[0] = *(const float4*)&As[kk][ty * 8];
            *(float4*)&a_[4] = *(const float4*)&As[kk][ty * 8 + 4];
            *(float4*)&b_[0] = *(const float4*)&Bs[kk][tx * 8];
            *(float4*)&b_[4] = *(const float4*)&Bs[kk][tx * 8 + 4];
            #pragma unroll
            for (int i = 0; i < 8; ++i)
                #pragma unroll
                for (int j = 0; j < 8; ++j)
                    acc[i][j] = fmaf(a_[i], b_[j], acc[i][j]);
        }
    }

    float bv[8];
    *(float4*)&bv[0] = *(const float4*)&bias[n0 + tx * 8];
    *(float4*)&bv[4] = *(const float4*)&bias[n0 + tx * 8 + 4];

    float sse_local = 0.0f;
    #pragma unroll
    for (int i = 0; i < 8; ++i) {
        const size_t row = (size_t)(m0 + ty * 8 + i);
        float out[8];
        #pragma unroll
        for (int j = 0; j < 8; ++j) {
            float v = acc[i][j] + bv[j];
            if (ACT == 1) v = 0.5f * v * (1.0f + erff(v * 0.70710678118654752440f));
            else if (ACT == 2) v = 1.0f / (1.0f + expf(-v));
            out[j] = v;
        }
        float* cp = C + row * N + n0 + tx * 8;
        *(float4*)&cp[0] = *(const float4*)&out[0];
        *(float4*)&cp[4] = *(const float4*)&out[4];
        if (ACT == 2) {
            const float* xp = Xref + row * N + n0 + tx * 8;
            #pragma unroll
            for (int j = 0; j < 8; ++j) {
                float d = xp[j] - out[j];
                sse_local = fmaf(d, d, sse_local);
            }
        }
    }

    if (ACT == 2) {
        #pragma unroll
        for (int off = 32; off > 0; off >>= 1)
            sse_local += __shfl_down(sse_local, off);
        if ((tid & 63) == 0) red[tid >> 6] = sse_local;
        __syncthreads();
        if (tid == 0) atomicAdd(sse_acc, red[0] + red[1] + red[2] + red[3]);
    }
}

// Scoring: factor[q,c] = sum_d Z[q,d]*E[c,d]; argmax over c (first-index ties).
// Z: [131072, 256], E: [1024, 256]. One block handles 128 rows, loops 8 chunks
// of 128 codes with the same tile structure as gemm_nt, folding a running
// (max, idx) per row.
__global__ __launch_bounds__(256) void score_argmax(
    const float* __restrict__ Z, const float* __restrict__ E,
    int* __restrict__ idx_out)
{
    __shared__ float As[BK][BM + 4];
    __shared__ float Bs[BK][BN + 4];
    __shared__ float rv[BM][17];
    __shared__ int   ri[BM][17];

    const int tid = threadIdx.x;
    const int tx = tid & 15;
    const int ty = tid >> 4;
    const int m0 = blockIdx.x * BM;
    const int lr = tid >> 2;
    const int lk = (tid & 3) << 2;

    const float* Ap = Z + (size_t)(m0 + lr) * 256 + lk;

    float best[8]; int besti[8];
    #pragma unroll
    for (int i = 0; i < 8; ++i) { best[i] = -3.4e38f; besti[i] = 0; }

    for (int c0 = 0; c0 < 1024; c0 += BN) {
        float acc[8][8];
        #pragma unroll
        for (int i = 0; i < 8; ++i)
            #pragma unroll
            for (int j = 0; j < 8; ++j) acc[i][j] = 0.0f;

        const float* Bp = E + (size_t)(c0 + lr) * 256 + lk;
        for (int k0 = 0; k0 < 256; k0 += BK) {
            float4 a0 = *(const float4*)(Ap + k0);
            float4 a1 = *(const float4*)(Ap + k0 + (size_t)64 * 256);
            float4 b0 = *(const float4*)(Bp + k0);
            float4 b1 = *(const float4*)(Bp + k0 + (size_t)64 * 256);
            __syncthreads();
            As[lk+0][lr]    = a0.x; As[lk+1][lr]    = a0.y; As[lk+2][lr]    = a0.z; As[lk+3][lr]    = a0.w;
            As[lk+0][lr+64] = a1.x; As[lk+1][lr+64] = a1.y; As[lk+2][lr+64] = a1.z; As[lk+3][lr+64] = a1.w;
            Bs[lk+0][lr]    = b0.x; Bs[lk+1][lr]    = b0.y; Bs[lk+2][lr]    = b0.z; Bs[lk+3][lr]    = b0.w;
            Bs[lk+0][lr+64] = b1.x; Bs[lk+1][lr+64] = b1.y; Bs[lk+2][lr+64] = b1.z; Bs[lk+3][lr+64] = b1.w;
            __syncthreads();
            #pragma unroll
            for (int kk = 0; kk < BK; ++kk) {
                float a_[8], b_[8];
                *(float4*)&a_[0] = *(const float4*)&As[kk][ty * 8];
                *(float4*)&a_[4] = *(const float4*)&As[kk][ty * 8 + 4];
                *(float4*)&b_[0] = *(const float4*)&Bs[kk][tx * 8];
                *(float4*)&b_[4] = *(const float4*)&Bs[kk][tx * 8 + 4];
                #pragma unroll
                for (int i = 0; i < 8; ++i)
                    #pragma unroll
                    for (int j = 0; j < 8; ++j)
                        acc[i][j] = fmaf(a_[i], b_[j], acc[i][j]);
            }
        }
        // fold into running argmax; cols visited in increasing order per thread,
        // strict > keeps the first max (jnp.argmax semantics)
        #pragma unroll
        for (int j = 0; j < 8; ++j) {
            const int col = c0 + tx * 8 + j;
            #pragma unroll
            for (int i = 0; i < 8; ++i) {
                if (acc[i][j] > best[i]) { best[i] = acc[i][j]; besti[i] = col; }
            }
        }
    }

    #pragma unroll
    for (int i = 0; i < 8; ++i) { rv[ty * 8 + i][tx] = best[i]; ri[ty * 8 + i][tx] = besti[i]; }
    __syncthreads();
    if (tid < BM) {
        float bvv = rv[tid][0]; int bii = ri[tid][0];
        #pragma unroll
        for (int t = 1; t < 16; ++t) {
            float v = rv[tid][t]; int ii = ri[tid][t];
            if (v > bvv || (v == bvv && ii < bii)) { bvv = v; bii = ii; }
        }
        idx_out[m0 + tid] = bii;
    }
}

// z_q gather + one-hot scatter + sum((z_e - z_q)^2). One block = one query row.
__global__ __launch_bounds__(256) void gather_zq(
    const float* __restrict__ Z, const float* __restrict__ E,
    const int* __restrict__ idx, float* __restrict__ Zq,
    float* __restrict__ onehot, float* __restrict__ acc)
{
    __shared__ float red[4];
    const size_t g = (size_t)blockIdx.x * 256 + threadIdx.x;
    const int q = (int)(g >> 8);
    const int d = (int)(g & 255);
    const int c = idx[q];
    const float e = E[(size_t)c * 256 + d];
    const float z = Z[g];
    Zq[g] = e;
    if (d == 0) onehot[(size_t)q * 1024 + c] = 1.0f;
    float v = (z - e) * (z - e);
    #pragma unroll
    for (int off = 32; off > 0; off >>= 1) v += __shfl_down(v, off);
    if ((threadIdx.x & 63) == 0) red[threadIdx.x >> 6] = v;
    __syncthreads();
    if (threadIdx.x == 0) atomicAdd(acc + 1, red[0] + red[1] + red[2] + red[3]);
}

__global__ void finalize_loss(const float* __restrict__ acc, float* __restrict__ out)
{
    const float m1 = acc[0] * (1.0f / (4096.0f * 3072.0f));
    const float m2 = acc[1] * (1.0f / (4096.0f * 32.0f * 256.0f));
    out[0] = (m1 + 1.25f * m2) * (1.0f / 4096.0f);
}

extern "C" void kernel_launch(void* const* d_in, const int* in_sizes, int n_in,
                              void* d_out, int out_size, void* d_ws, size_t ws_size,
                              hipStream_t stream)
{
    const float* x   = (const float*)d_in[0];
    const float* E   = (const float*)d_in[1];
    const float* ew1 = (const float*)d_in[2];
    const float* eb1 = (const float*)d_in[3];
    const float* ew2 = (const float*)d_in[4];
    const float* eb2 = (const float*)d_in[5];
    const float* ew3 = (const float*)d_in[6];
    const float* eb3 = (const float*)d_in[7];
    const float* dw1 = (const float*)d_in[8];
    const float* db1 = (const float*)d_in[9];
    const float* dw2 = (const float*)d_in[10];
    const float* db2 = (const float*)d_in[11];
    const float* dw3 = (const float*)d_in[12];
    const float* db3 = (const float*)d_in[13];

    float* outf   = (float*)d_out;
    float* xpred  = outf;                                       // 4096*3072
    float* onehot = outf + (size_t)4096 * 3072;                 // 4096*32*1024
    float* loss   = onehot + (size_t)4096 * 32 * 1024;          // 1

    float* ws  = (float*)d_ws;
    float* H1  = ws;                                            // 16777216
    float* H2  = H1 + (size_t)16777216;                         // 16777216
    float* ZE  = H2 + (size_t)16777216;                         // 33554432
    float* ZQ  = ZE + (size_t)33554432;                         // 33554432
    int*   IDX = (int*)(ZQ + (size_t)33554432);                 // 131072
    float* ACC = (float*)(IDX + 131072);                        // 2 floats

    hipMemsetAsync(ACC, 0, 2 * sizeof(float), stream);
    hipMemsetAsync(onehot, 0, (size_t)4096 * 32 * 1024 * sizeof(float), stream);

    dim3 blk(256);
    // encoder
    gemm_nt<1><<<dim3(4096 / BN, 4096 / BM), blk, 0, stream>>>(x,  ew1, eb1, H1, 4096, 4096, 3072, nullptr, nullptr);
    gemm_nt<1><<<dim3(4096 / BN, 4096 / BM), blk, 0, stream>>>(H1, ew2, eb2, H2, 4096, 4096, 4096, nullptr, nullptr);
    gemm_nt<0><<<dim3(8192 / BN, 4096 / BM), blk, 0, stream>>>(H2, ew3, eb3, ZE, 4096, 8192, 4096, nullptr, nullptr);
    // codebook scoring + argmax, gather, one-hot, sse_z
    score_argmax<<<dim3(131072 / BM), blk, 0, stream>>>(ZE, E, IDX);
    gather_zq<<<dim3(131072), blk, 0, stream>>>(ZE, E, IDX, ZQ, onehot, ACC);
    // decoder (z_ss == z_q bitwise due to straight-through)
    gemm_nt<1><<<dim3(4096 / BN, 4096 / BM), blk, 0, stream>>>(ZQ, dw1, db1, H1, 4096, 4096, 8192, nullptr, nullptr);
    gemm_nt<1><<<dim3(4096 / BN, 4096 / BM), blk, 0, stream>>>(H1, dw2, db2, H2, 4096, 4096, 4096, nullptr, nullptr);
    gemm_nt<2><<<dim3(3072 / BN, 4096 / BM), blk, 0, stream>>>(H2, dw3, db3, xpred, 4096, 3072, 4096, x, ACC);
    finalize_loss<<<1, 1, 0, stream>>>(ACC, loss);
}